// Round 17
// baseline (112.276 us; speedup 1.0000x reference)
//
#include <hip/hip_runtime.h>

#define HH 1024
#define WW 1024
#define KK 9
#define PADK 4
#define TSX 16
#define TSY 8
#define NPX 128    // pixels per block
#define TROWS 16   // TSY + 2*PADK
#define TCOLS 24   // TSX + 2*PADK
#define NW 81
#define ROWB 5184  // 16 px * 324 B, contiguous per image row

#define SBAR __builtin_amdgcn_sched_barrier(0)

// R12's exact structure (16x8 px, 128 thr, single-pass weights, 48 KB LDS,
// 3 blocks/CU) with ONE variable changed: weight staging goes through the
// PLAIN load path (global_load_dwordx4 -> VGPR -> ds_write_b128) instead of
// global_load_lds. The 6.3 TB/s achievable-BW figure was measured on plain
// loads; five DMA-path designs all converge at ~5.1 TB/s. This isolates
// whether the global_load_lds fill path is the ~20% gap.
__global__ __launch_bounds__(128) void denoiser_kpn(
    const float* __restrict__ unet, const float* __restrict__ cnn,
    float* __restrict__ out) {
  __shared__ __attribute__((aligned(16))) float wlds[NPX * NW];  // 41472 B
  __shared__ float4 tile[TROWS][TCOLS + 1];                      // 6400 B

  const int tid = threadIdx.x;   // 0..127
  const int lane = tid & 63;
  const int wv = tid >> 6;       // wave 0/1
  const int tx = tid & 15;
  const int ty = tid >> 4;       // 0..7
  const int px0 = blockIdx.x * TSX;
  const int py0 = blockIdx.y * TSY;

  // ---- 1. Tile global loads FIRST (oldest VMEM -> their wait leaves the
  //         weight loads in flight): 384 entries / 128 thr. ----
  float tr_[3][3];
#pragma unroll
  for (int i = 0; i < 3; ++i) {
    const int idx = tid + 128 * i;  // 0..383 over 16x24
    const int r = idx / TCOLS;
    const int c = idx - r * TCOLS;
    int gy = py0 - PADK + r;
    gy = gy < 0 ? -gy : (gy >= HH ? 2 * HH - 2 - gy : gy);
    int gx = px0 - PADK + c;
    gx = gx < 0 ? -gx : (gx >= WW ? 2 * WW - 2 - gx : gx);
    __builtin_memcpy(&tr_[i][0], unet + ((size_t)gy * WW + gx) * 3, 12);
  }
  SBAR;

  // ---- 2. Weight loads -> VGPRs (plain dwordx4, perfectly coalesced:
  //         each instr = 64 lanes x 16 B = 1024 contiguous bytes). Wave wv
  //         stages its own rows 4wv..4wv+3; 24 VMEM ops, 96 VGPRs. ----
  float4 wr[4][5];
  float4 wt[4];
#pragma unroll
  for (int rr = 0; rr < 4; ++rr) {
    const int r = wv * 4 + rr;
    const float4* s =
        (const float4*)(cnn + ((size_t)(py0 + r) * WW + px0) * NW);
#pragma unroll
    for (int i = 0; i < 5; ++i) wr[rr][i] = s[lane + 64 * i];
    if (lane < 4) wt[rr] = s[320 + lane];  // 64 B row tail
  }
  SBAR;

  // ---- 3. Tile -> LDS (compiler waits only the 3 tile loads; 24 weight
  //         loads stay outstanding across the barrier). ----
#pragma unroll
  for (int i = 0; i < 3; ++i) {
    const int idx = tid + 128 * i;
    const int r = idx / TCOLS;
    const int c = idx - r * TCOLS;
    tile[r][c] = make_float4(tr_[i][0], tr_[i][1], tr_[i][2], 0.0f);
  }
  SBAR;
  asm volatile("s_waitcnt lgkmcnt(0)" ::: "memory");
  __builtin_amdgcn_s_barrier();  // publish tile; weight loads still flying
  SBAR;

  // ---- 4. Weight regs -> LDS (own-wave data; conflict-free b128 writes). --
  asm volatile("s_waitcnt vmcnt(0)" ::: "memory");
  SBAR;
#pragma unroll
  for (int rr = 0; rr < 4; ++rr) {
    const int r = wv * 4 + rr;
    float4* d = (float4*)((char*)wlds + r * ROWB);
#pragma unroll
    for (int i = 0; i < 5; ++i) d[lane + 64 * i] = wr[rr][i];
    if (lane < 4) d[320 + lane] = wt[rr];
  }
  asm volatile("s_waitcnt lgkmcnt(0)" ::: "memory");  // own writes visible
  SBAR;

  // ---- 5. 81 taps (unchanged): tile b128 conflict-free, weight b32
  //         lane-stride 81 dwords -> 2-way = free. ----
  float ax = 0.0f, ay = 0.0f, az = 0.0f;
  const float* wrow = wlds + tid * NW;
#pragma unroll
  for (int ki = 0; ki < KK; ++ki)
#pragma unroll
    for (int kj = 0; kj < KK; ++kj) {
      const float4 pv = tile[ty + ki][tx + kj];
      const float w = wrow[ki * KK + kj];
      ax = fmaf(w, pv.x, ax);
      ay = fmaf(w, pv.y, ay);
      az = fmaf(w, pv.z, az);
    }

  const float o[3] = {ax, ay, az};
  __builtin_memcpy(out + ((size_t)(py0 + ty) * WW + px0 + tx) * 3, &o[0], 12);
}

extern "C" void kernel_launch(void* const* d_in, const int* in_sizes, int n_in,
                              void* d_out, int out_size, void* d_ws, size_t ws_size,
                              hipStream_t stream) {
  const float* unet = (const float*)d_in[0];  // [1024,1024,3] f32
  const float* cnn = (const float*)d_in[1];   // [1024,1024,81] f32
  float* out = (float*)d_out;                 // [1024,1024,3] f32
  dim3 grid(WW / TSX, HH / TSY);              // 64 x 128 = 8192 blocks
  dim3 block(NPX);
  denoiser_kpn<<<grid, block, 0, stream>>>(unet, cnn, out);
}

// Round 18
// 73.224 us; speedup vs baseline: 1.5333x; 1.5333x over previous
//
#include <hip/hip_runtime.h>

#define HH 1024
#define WW 1024
#define KK 9
#define PADK 4
#define TS 16        // 16x16 px block, 256 threads, 4 waves
#define TROWS 24     // TS + 2*PADK
#define TSTR 25      // float4 row stride (pad)
#define NW 81
#define ROWB 5184    // 16 px * 324 B contiguous per image row
#define CHF 5184     // chunk floats: 4 rows * 16 px * 81

#define GLDS(src, dst, w)                                              \
  __builtin_amdgcn_global_load_lds(                                    \
      (const __attribute__((address_space(1))) unsigned int*)(src),    \
      (__attribute__((address_space(3))) unsigned int*)(dst), w, 0, 0)

#define SBAR __builtin_amdgcn_sched_barrier(0)

// Bus-duty-cycle fix. 256-thr block = 16x16 px. Weights = 4 pixel-contiguous
// chunks (wave w's rows 4w..4w+3, 20.7 KB each, single-pass HBM) but only 2
// chunk buffers resident: chunks 0,1 DMA'd at prologue, chunks 2,3 at the
// mid-block barrier -> per-block demand spread over 2 burst points instead
// of R12's single burst (33% duty cycle -> measured 5.1 TB/s). 51 KB LDS ->
// 3 blocks/CU = 12 waves/CU (2x R12). Every weight DMA->read dependency is
// own-wave (per-wave vmcnt(0)); two raw s_barriers only (tile publish +
// buffer recycle); no block-wide vmcnt drain anywhere.
__global__ __launch_bounds__(256) void denoiser_kpn(
    const float* __restrict__ unet, const float* __restrict__ cnn,
    float* __restrict__ out) {
  __shared__ __attribute__((aligned(16))) float wbuf[2][CHF];  // 41472 B
  __shared__ float4 tile[TROWS][TSTR];                         // 9600 B

  const int tid = threadIdx.x;
  const int lane = tid & 63;
  const int wv = tid >> 6;        // wave 0..3; owns tile rows 4wv..4wv+3
  const int tx = lane & 15;
  const int ry = lane >> 4;       // row within the wave's 4-row band
  const int px0 = blockIdx.x * TS;
  const int py0 = blockIdx.y * TS;

  // Own-wave chunk DMA: 4 rows x (5 x 1024 B + 64 B tail) = 24 VMEM ops.
  auto wdma = [&](int w, int b) {
#pragma unroll
    for (int r = 0; r < 4; ++r) {
      const char* s =
          (const char*)(cnn + ((size_t)(py0 + 4 * w + r) * WW + px0) * NW);
      char* d = (char*)&wbuf[b][0] + r * ROWB;
#pragma unroll
      for (int i = 0; i < 5; ++i)
        GLDS(s + i * 1024 + lane * 16, d + i * 1024 + lane * 16, 16);
      if (lane < 4) GLDS(s + 5120 + lane * 16, d + 5120 + lane * 16, 16);
    }
  };

  // Own-wave compute: 64 px, 1 px/thread, full 81 taps; then store.
  auto compute = [&](int w, int b) {
    const float* wrow = &wbuf[b][ry * 1296 + tx * NW];  // bank 17*lane -> 2-way
    const int trow = 4 * w + ry;
    float ax = 0.f, ay = 0.f, az = 0.f;
#pragma unroll
    for (int ki = 0; ki < KK; ++ki)
#pragma unroll
      for (int kj = 0; kj < KK; ++kj) {
        const float4 pv = tile[trow + ki][tx + kj];
        const float wgt = wrow[ki * KK + kj];
        ax = fmaf(wgt, pv.x, ax);
        ay = fmaf(wgt, pv.y, ay);
        az = fmaf(wgt, pv.z, az);
      }
    const float o[3] = {ax, ay, az};
    __builtin_memcpy(out + ((size_t)(py0 + trow) * WW + px0 + tx) * 3, &o[0], 12);
  };

  // ---- Prologue: tile gloads (oldest VMEM), chunks 0,1 DMA, tile->LDS. ----
  float tr_[3][3];
#pragma unroll
  for (int i = 0; i < 3; ++i) {
    int e = tid + 256 * i;  // 576 entries over 24x24
    if (e > 575) e = 575;   // dup load; write predicated below
    const int r = e / TROWS;
    const int c = e - r * TROWS;
    int gy = py0 - PADK + r;
    gy = gy < 0 ? -gy : (gy >= HH ? 2 * HH - 2 - gy : gy);
    int gx = px0 - PADK + c;
    gx = gx < 0 ? -gx : (gx >= WW ? 2 * WW - 2 - gx : gx);
    __builtin_memcpy(&tr_[i][0], unet + ((size_t)gy * WW + gx) * 3, 12);
  }
  SBAR;
  if (wv == 0) wdma(0, 0);
  if (wv == 1) wdma(1, 1);
  SBAR;
#pragma unroll
  for (int i = 0; i < 3; ++i) {  // compiler waits only the 3 tile loads
    const int idx = tid + 256 * i;
    if (idx < 576) {
      const int r = idx / TROWS;
      const int c = idx - r * TROWS;
      tile[r][c] = make_float4(tr_[i][0], tr_[i][1], tr_[i][2], 0.0f);
    }
  }
  SBAR;
  asm volatile("s_waitcnt lgkmcnt(0)" ::: "memory");
  __builtin_amdgcn_s_barrier();  // T: tile published; chunk DMAs ride
  SBAR;

  // ---- Phase 0: waves 0,1 compute their chunks concurrently. ----
  if (wv < 2) {
    asm volatile("s_waitcnt vmcnt(0)" ::: "memory");  // own 24 DMA ops
    SBAR;
    compute(wv, wv);
  }
  SBAR;
  __builtin_amdgcn_s_barrier();  // A: buf0,buf1 free (c0,c1 fully read)
  SBAR;

  // ---- Phase 1: waves 2,3 DMA + compute concurrently (own-wave deps). ----
  if (wv >= 2) {
    wdma(wv, wv - 2);
    SBAR;
    asm volatile("s_waitcnt vmcnt(0)" ::: "memory");
    SBAR;
    compute(wv, wv - 2);
  }
}

extern "C" void kernel_launch(void* const* d_in, const int* in_sizes, int n_in,
                              void* d_out, int out_size, void* d_ws, size_t ws_size,
                              hipStream_t stream) {
  const float* unet = (const float*)d_in[0];  // [1024,1024,3] f32
  const float* cnn = (const float*)d_in[1];   // [1024,1024,81] f32
  float* out = (float*)d_out;                 // [1024,1024,3] f32
  dim3 grid(WW / TS, HH / TS);                // 64 x 64 = 4096 blocks
  dim3 block(256);
  denoiser_kpn<<<grid, block, 0, stream>>>(unet, cnn, out);
}

// Round 19
// 71.512 us; speedup vs baseline: 1.5700x; 1.0239x over previous
//
#include <hip/hip_runtime.h>

#define HH 1024
#define WW 1024
#define KK 9
#define PADK 4
#define TSX 16
#define TSY 8
#define NPX 128    // pixels per block
#define TROWS 16   // TSY + 2*PADK
#define TCOLS 24   // TSX + 2*PADK
#define NW 81
#define ROWB 5184  // 16 px * 324 B, contiguous per image row

#define GLDS(src, dst, w)                                              \
  __builtin_amdgcn_global_load_lds(                                    \
      (const __attribute__((address_space(1))) unsigned int*)(src),    \
      (__attribute__((address_space(3))) unsigned int*)(dst), w, 0, 0)

// FINAL (= R12, best of 8 structural variants at 71.3 us, ~5.1 TB/s
// effective on the 365 MB stream = 81% of copy ceiling).
// Single-pass KPN: 128-thread block = 16x8 pixels. ALL weights staged once
// via global_load_lds (no k-chunking -> each cnn byte fetched exactly once;
// multi-pass variants measured +28-70% slower). Per image row 5184
// contiguous bytes: 5x width-16 DMA + 16-lane width-4 tail; wave w stages
// exactly the rows it consumes (ty in [4w,4w+4)) -> weight-wait is per-wave
// vmcnt(0), no cross-wave weight barrier. Tile published with lgkmcnt(0) +
// raw s_barrier (weight DMA rides across it). LDS 46.75 KB -> 3 blocks/CU.
// Nulled levers: occupancy 6/10/12 w/CU flat; deeper pipelining flat-to-
// worse; NT hint null; XCD swizzle null; reg-staging 1.6x worse.
__global__ __launch_bounds__(128) void denoiser_kpn(
    const float* __restrict__ unet, const float* __restrict__ cnn,
    float* __restrict__ out) {
  __shared__ __attribute__((aligned(16))) float wlds[NPX * NW];  // 41472 B
  __shared__ float4 tile[TROWS][TCOLS + 1];                      // 6400 B

  const int tid = threadIdx.x;   // 0..127
  const int lane = tid & 63;
  const int wv = tid >> 6;       // wave 0/1
  const int tx = tid & 15;
  const int ty = tid >> 4;       // 0..7
  const int px0 = blockIdx.x * TSX;
  const int py0 = blockIdx.y * TSY;

  // ---- 1. Tile global loads first (into VGPRs): 384 entries / 128 thr. ----
  float tr_[3][3];
#pragma unroll
  for (int i = 0; i < 3; ++i) {
    const int idx = tid + 128 * i;        // 0..383
    const int r = idx / TCOLS;
    const int c = idx - r * TCOLS;
    int gy = py0 - PADK + r;
    gy = gy < 0 ? -gy : (gy >= HH ? 2 * HH - 2 - gy : gy);
    int gx = px0 - PADK + c;
    gx = gx < 0 ? -gx : (gx >= WW ? 2 * WW - 2 - gx : gx);
    __builtin_memcpy(&tr_[i][0], unet + ((size_t)gy * WW + gx) * 3, 12);
  }
  __builtin_amdgcn_sched_barrier(0);

  // ---- 2. Weight DMA: wave wv stages image rows 4wv..4wv+3 (its own ty
  //         range). Row = 5184 B contiguous: 5 x 1024 B + 64 B tail. ----
#pragma unroll
  for (int rr = 0; rr < 4; ++rr) {
    const int r = wv * 4 + rr;
    const char* s = (const char*)(cnn + ((size_t)(py0 + r) * WW + px0) * NW);
    char* d = (char*)wlds + r * ROWB;
#pragma unroll
    for (int i = 0; i < 5; ++i)
      GLDS(s + i * 1024 + lane * 16, d + i * 1024 + lane * 16, 16);
    if (lane < 16) GLDS(s + 5120 + lane * 4, d + 5120 + lane * 4, 4);
  }
  __builtin_amdgcn_sched_barrier(0);

  // ---- 3. Tile -> LDS (compiler waits the tile loads; weight DMA rides). --
#pragma unroll
  for (int i = 0; i < 3; ++i) {
    const int idx = tid + 128 * i;
    const int r = idx / TCOLS;
    const int c = idx - r * TCOLS;
    tile[r][c] = make_float4(tr_[i][0], tr_[i][1], tr_[i][2], 0.0f);
  }
  __builtin_amdgcn_sched_barrier(0);
  asm volatile("s_waitcnt lgkmcnt(0)" ::: "memory");
  __builtin_amdgcn_s_barrier();  // publish tile; weight DMA still in flight
  __builtin_amdgcn_sched_barrier(0);
  asm volatile("s_waitcnt vmcnt(0)" ::: "memory");  // own rows' weights landed
  __builtin_amdgcn_sched_barrier(0);

  // ---- 4. 81 taps. Weight reads: lane stride 81 dwords -> 2/bank = free.
  //         Tile b128: (ty+tx) mod 8 -> exactly 8 lanes/bank-group = free. --
  float ax = 0.0f, ay = 0.0f, az = 0.0f;
  const float* wrow = wlds + tid * NW;
#pragma unroll
  for (int ki = 0; ki < KK; ++ki)
#pragma unroll
    for (int kj = 0; kj < KK; ++kj) {
      const float4 pv = tile[ty + ki][tx + kj];
      const float w = wrow[ki * KK + kj];
      ax = fmaf(w, pv.x, ax);
      ay = fmaf(w, pv.y, ay);
      az = fmaf(w, pv.z, az);
    }

  const float o[3] = {ax, ay, az};
  __builtin_memcpy(out + ((size_t)(py0 + ty) * WW + px0 + tx) * 3, &o[0], 12);
}

extern "C" void kernel_launch(void* const* d_in, const int* in_sizes, int n_in,
                              void* d_out, int out_size, void* d_ws, size_t ws_size,
                              hipStream_t stream) {
  const float* unet = (const float*)d_in[0];  // [1024,1024,3] f32
  const float* cnn = (const float*)d_in[1];   // [1024,1024,81] f32
  float* out = (float*)d_out;                 // [1024,1024,3] f32
  dim3 grid(WW / TSX, HH / TSY);              // 64 x 128 = 8192 blocks
  dim3 block(NPX);
  denoiser_kpn<<<grid, block, 0, stream>>>(unet, cnn, out);
}